// Round 17
// baseline (126.050 us; speedup 1.0000x reference)
//
#include <hip/hip_runtime.h>
#include <hip/hip_bf16.h>

#define IN_F 128
#define OUT_F 32
#define BSHIFT 7
#define NPB 128            // nodes per bucket (dst >> 7)
#define BCHUNK 4096        // edges per bin chunk
#define BIN_THREADS 512    // 52KB LDS -> 3 blocks/CU; 782/768 slots = 1.02 rounds
#define GAT_THREADS 512
#define TILE 2048          // recs per LDS tile in fused sort+gather
#define MAXBIN 1024
#define CAP 5120           // per-bucket region capacity (mean 4092 + 16 sigma)

static __device__ inline unsigned short f2bf_rne(float f) {
    unsigned u = __float_as_uint(f);
    unsigned r = u + 0x7FFF + ((u >> 16) & 1);   // round-to-nearest-even
    return (unsigned short)(r >> 16);
}

// ---------------- K1: h = x @ W, output bf16 (W staged in LDS) ----------------
__global__ void gcn_gemm_h(const float* __restrict__ x, const float* __restrict__ W,
                           unsigned short* __restrict__ h, int n_rows)
{
    __shared__ float Wl[IN_F * OUT_F];           // 16 KB
    const int tid = threadIdx.x;
    const float4* W4 = (const float4*)W;
    float4* Wl4 = (float4*)Wl;
    #pragma unroll
    for (int i = 0; i < 4; ++i)
        Wl4[tid + i * 256] = W4[tid + i * 256];
    __syncthreads();

    const int c4   = tid & 7;
    const int rloc = tid >> 3;
    const int row  = blockIdx.x * 32 + rloc;
    if (row >= n_rows) return;

    const float4* xr = (const float4*)(x + (size_t)row * IN_F);
    float4 acc = {0.f, 0.f, 0.f, 0.f};
    #pragma unroll
    for (int k4 = 0; k4 < IN_F / 4; ++k4) {
        const float4 xv = xr[k4];
        #pragma unroll
        for (int j = 0; j < 4; ++j) {
            const int k = k4 * 4 + j;
            const float4 wv = *(const float4*)(&Wl[k * OUT_F + c4 * 4]);
            const float xs = (&xv.x)[j];
            acc.x += xs * wv.x;
            acc.y += xs * wv.y;
            acc.z += xs * wv.z;
            acc.w += xs * wv.w;
        }
    }
    ushort4 o = { f2bf_rne(acc.x), f2bf_rne(acc.y), f2bf_rne(acc.z), f2bf_rne(acc.w) };
    *(ushort4*)(&h[(size_t)row * OUT_F + c4 * 4]) = o;
}

// ---------------- K2: in-LDS counting sort by bucket + atomic-reserved copy-out ----
// 512 threads, 52 KB LDS -> 3 blocks/CU -> 782 blocks in 1.02 rounds (tail fix).
// Scan handles 2 buckets per thread (pair-sum shfl scan + split).
// Record: {src | (dstLocal<<17), w_bits}  (src < 2^17, dstLocal < 2^7)
__global__ __launch_bounds__(BIN_THREADS)
void gcn_bin(const int* __restrict__ esrc, const int* __restrict__ edst,
             const float* __restrict__ ew, int* __restrict__ gcur,
             int2* __restrict__ recs, int n_edges, int nb)
{
    __shared__ int2 sorted[BCHUNK];              // 32 KB
    __shared__ unsigned short binOf[BCHUNK];     // 8 KB
    __shared__ int hist[MAXBIN];                 // 4 KB
    __shared__ int cursor[MAXBIN];               // 4 KB
    __shared__ int gbase[MAXBIN];                // 4 KB
    __shared__ int wpart[8];
    __shared__ int wpre[8];

    const int tid = threadIdx.x;
    const int k   = blockIdx.x;
    const int base  = k * BCHUNK;
    const int count = min(BCHUNK, n_edges - base);

    for (int i = tid; i < nb; i += BIN_THREADS) hist[i] = 0;
    __syncthreads();
    for (int i = tid; i < count; i += BIN_THREADS)
        atomicAdd(&hist[edst[base + i] >> BSHIFT], 1);
    __syncthreads();

    // pair scan: thread t owns buckets 2t and 2t+1 (covers 1024 >= nb)
    const int b0 = tid * 2, b1 = tid * 2 + 1;
    const int h0 = (b0 < nb) ? hist[b0] : 0;
    const int h1 = (b1 < nb) ? hist[b1] : 0;
    const int v = h0 + h1;
    int sc = v;
    #pragma unroll
    for (int off = 1; off < 64; off <<= 1) {
        const int t = __shfl_up(sc, off, 64);
        if ((tid & 63) >= off) sc += t;
    }
    if ((tid & 63) == 63) wpart[tid >> 6] = sc;
    __syncthreads();
    if (tid < 8) {
        const int pv = wpart[tid];
        int ps = pv;
        #pragma unroll
        for (int off = 1; off < 8; off <<= 1) {
            const int t = __shfl_up(ps, off, 64);
            if (tid >= off) ps += t;
        }
        wpre[tid] = ps - pv;
    }
    __syncthreads();
    {
        const int P = sc - v + wpre[tid >> 6];     // exclusive prefix of pair
        if (b0 < nb) {
            cursor[b0] = P;
            int gb = b0 * CAP;
            if (h0 > 0) gb += atomicAdd(&gcur[b0], h0);
            gbase[b0] = gb - P;
        }
        if (b1 < nb) {
            const int P1 = P + h0;
            cursor[b1] = P1;
            int gb = b1 * CAP;
            if (h1 > 0) gb += atomicAdd(&gcur[b1], h1);
            gbase[b1] = gb - P1;
        }
    }
    __syncthreads();

    // scatter into LDS sorted order (edges re-read, L2-hot)
    for (int i = tid; i < count; i += BIN_THREADS) {
        const int e = base + i;
        const int d = edst[e];
        const int bk = d >> BSHIFT;
        const int pos = atomicAdd(&cursor[bk], 1);
        sorted[pos] = make_int2(esrc[e] | ((d & (NPB - 1)) << 17), __float_as_int(ew[e]));
        binOf[pos]  = (unsigned short)bk;
    }
    __syncthreads();

    // linear copy-out: consecutive i within a run -> consecutive global addrs
    for (int i = tid; i < count; i += BIN_THREADS)
        recs[gbase[binOf[i]] + i] = sorted[i];
}

// ---------------- K3: fused per-bucket LDS sort + packed register gather ----------
// 512 threads, ~34 KB LDS -> 4 blocks/CU. 32 groups of 16 lanes; each group owns
// 4 nodes; lane handles 2 packed bf16 channels (dword load, 2 FMA); 4-deep unroll.
__global__ __launch_bounds__(GAT_THREADS)
void gcn_sort_gather(const unsigned short* __restrict__ h,
                     const int2* __restrict__ recs,
                     const int* __restrict__ gcur,
                     float* __restrict__ out, int n_nodes)
{
    __shared__ int2 sbuf[TILE];       // 16 KB
    __shared__ int2 sorted[TILE];     // 16 KB
    __shared__ int hist[NPB];
    __shared__ int nbeg[NPB];
    __shared__ int cursor[NPB];
    __shared__ int wpart[2];

    const int b   = blockIdx.x;
    const int tid = threadIdx.x;
    const int s   = b * CAP;
    const int cnt = gcur[b];           // records written for this bucket
    const int grp = tid >> 4;          // 0..31: group of 16 lanes, owns 4 nodes
    const int c2  = tid & 15;          // channel pair (2*c2, 2*c2+1)
    const size_t hoff = (size_t)(c2 << 1);

    float accx[4] = {0.f, 0.f, 0.f, 0.f};
    float accy[4] = {0.f, 0.f, 0.f, 0.f};

    for (int t0 = 0; t0 < cnt; t0 += TILE) {
        const int tc = min(TILE, cnt - t0);
        __syncthreads();               // previous tile's gather done before reuse
        if (tid < NPB) hist[tid] = 0;
        __syncthreads();
        for (int i = tid; i < tc; i += GAT_THREADS) {
            const int2 r = recs[s + t0 + i];
            sbuf[i] = r;
            atomicAdd(&hist[(r.x >> 17) & (NPB - 1)], 1);
        }
        __syncthreads();

        // exclusive scan over NPB=128 entries: shfl scan + 2-wave combine
        const int v = (tid < NPB) ? hist[tid] : 0;
        int sc = v;
        #pragma unroll
        for (int off = 1; off < 64; off <<= 1) {
            const int t = __shfl_up(sc, off, 64);
            if ((tid & 63) >= off) sc += t;
        }
        if (tid < NPB && (tid & 63) == 63) wpart[tid >> 6] = sc;
        __syncthreads();
        if (tid < NPB) {
            const int beg = sc - v + ((tid >= 64) ? wpart[0] : 0);
            nbeg[tid]   = beg;
            cursor[tid] = beg;
        }
        __syncthreads();

        for (int i = tid; i < tc; i += GAT_THREADS) {
            const int2 r = sbuf[i];
            const int pos = atomicAdd(&cursor[(r.x >> 17) & (NPB - 1)], 1);
            sorted[pos] = r;
        }
        __syncthreads();

        // gather: 4 nodes per 16-lane group; 4-deep pipelined inner loop
        #pragma unroll
        for (int n = 0; n < 4; ++n) {
            const int dL = (grp << 2) + n;
            int i = nbeg[dL];
            const int e = i + hist[dL];
            float ax = 0.f, ay = 0.f;
            for (; i + 4 <= e; i += 4) {
                const int2 r0 = sorted[i];
                const int2 r1 = sorted[i + 1];
                const int2 r2 = sorted[i + 2];
                const int2 r3 = sorted[i + 3];
                const unsigned v0 = *(const unsigned*)(h + (((size_t)(r0.x & 0x1FFFF)) << 5) + hoff);
                const unsigned v1 = *(const unsigned*)(h + (((size_t)(r1.x & 0x1FFFF)) << 5) + hoff);
                const unsigned v2 = *(const unsigned*)(h + (((size_t)(r2.x & 0x1FFFF)) << 5) + hoff);
                const unsigned v3 = *(const unsigned*)(h + (((size_t)(r3.x & 0x1FFFF)) << 5) + hoff);
                const float w0 = __int_as_float(r0.y);
                const float w1 = __int_as_float(r1.y);
                const float w2 = __int_as_float(r2.y);
                const float w3 = __int_as_float(r3.y);
                ax += w0 * __uint_as_float(v0 << 16);
                ay += w0 * __uint_as_float(v0 & 0xFFFF0000u);
                ax += w1 * __uint_as_float(v1 << 16);
                ay += w1 * __uint_as_float(v1 & 0xFFFF0000u);
                ax += w2 * __uint_as_float(v2 << 16);
                ay += w2 * __uint_as_float(v2 & 0xFFFF0000u);
                ax += w3 * __uint_as_float(v3 << 16);
                ay += w3 * __uint_as_float(v3 & 0xFFFF0000u);
            }
            for (; i < e; ++i) {
                const int2 r = sorted[i];
                const unsigned hv = *(const unsigned*)(h + (((size_t)(r.x & 0x1FFFF)) << 5) + hoff);
                const float w = __int_as_float(r.y);
                ax += w * __uint_as_float(hv << 16);
                ay += w * __uint_as_float(hv & 0xFFFF0000u);
            }
            accx[n] += ax;
            accy[n] += ay;
        }
    }

    const int nodeBase = b << BSHIFT;
    #pragma unroll
    for (int n = 0; n < 4; ++n) {
        const int node = nodeBase + (grp << 2) + n;
        if (node < n_nodes) {
            float2 o = { accx[n], accy[n] };
            *(float2*)(out + ((size_t)node << 5) + (c2 << 1)) = o;
        }
    }
}

// ---------------- Fallback (no/small ws): fused, atomics into out ----------------
__global__ void gcn_fused_fallback(const float* __restrict__ x, const float* __restrict__ W,
                                   const int* __restrict__ esrc,
                                   const int* __restrict__ edst,
                                   const float* __restrict__ ew,
                                   float* __restrict__ out,
                                   long long total_units)
{
    __shared__ float Wl[IN_F * OUT_F];
    const int tid = threadIdx.x;
    const float4* W4 = (const float4*)W;
    float4* Wl4 = (float4*)Wl;
    #pragma unroll
    for (int i = 0; i < 4; ++i)
        Wl4[tid + i * 256] = W4[tid + i * 256];
    __syncthreads();

    long long u = (long long)blockIdx.x * blockDim.x + threadIdx.x;
    if (u >= total_units) return;
    const int e = (int)(u >> 5);
    const int c = (int)(u & 31);
    const int s  = esrc[e];
    const int d  = edst[e];
    const float w = ew[e];

    const float4* xr = (const float4*)(x + (size_t)s * IN_F);
    float acc = 0.f;
    #pragma unroll
    for (int k4 = 0; k4 < IN_F / 4; ++k4) {
        const float4 xv = xr[k4];
        acc += xv.x * Wl[(k4 * 4 + 0) * OUT_F + c];
        acc += xv.y * Wl[(k4 * 4 + 1) * OUT_F + c];
        acc += xv.z * Wl[(k4 * 4 + 2) * OUT_F + c];
        acc += xv.w * Wl[(k4 * 4 + 3) * OUT_F + c];
    }
    atomicAdd(out + (size_t)d * OUT_F + c, w * acc);
}

static inline size_t align_up(size_t v, size_t a) { return (v + a - 1) & ~(a - 1); }

extern "C" void kernel_launch(void* const* d_in, const int* in_sizes, int n_in,
                              void* d_out, int out_size, void* d_ws, size_t ws_size,
                              hipStream_t stream)
{
    const float* x  = (const float*)d_in[0];
    const float* W  = (const float*)d_in[1];
    const int* esrc = (const int*)d_in[2];
    const int* edst = (const int*)d_in[3];
    const float* ew = (const float*)d_in[4];
    float* out = (float*)d_out;

    const int n_nodes = in_sizes[0] / IN_F;
    const int n_edges = in_sizes[2];

    const int nb       = (n_nodes + NPB - 1) >> BSHIFT;    // 782
    const int n_chunks = (n_edges + BCHUNK - 1) / BCHUNK;  // 782
    const int avg_per_bucket = n_edges / nb;

    const size_t h_bytes    = align_up((size_t)n_nodes * OUT_F * sizeof(unsigned short), 256);
    const size_t cur_bytes  = align_up((size_t)nb * sizeof(int), 256);
    const size_t recs_bytes = align_up((size_t)nb * CAP * sizeof(int2) + 16, 256);
    const size_t need = h_bytes + cur_bytes + recs_bytes;

    if (ws_size >= need && nb <= MAXBIN && avg_per_bucket + 16 * 64 < CAP) {
        char* p = (char*)d_ws;
        unsigned short* h = (unsigned short*)p;  p += h_bytes;
        int* gcur     = (int*)p;                 p += cur_bytes;
        int2* recs    = (int2*)p;

        hipMemsetAsync(gcur, 0, (size_t)nb * sizeof(int), stream);

        const int gemm_blocks = (n_nodes + 31) / 32;
        gcn_gemm_h<<<gemm_blocks, 256, 0, stream>>>(x, W, h, n_nodes);

        gcn_bin<<<n_chunks, BIN_THREADS, 0, stream>>>(esrc, edst, ew, gcur,
                                                      recs, n_edges, nb);

        gcn_sort_gather<<<nb, GAT_THREADS, 0, stream>>>(h, recs, gcur, out, n_nodes);
    } else {
        hipMemsetAsync(d_out, 0, (size_t)out_size * sizeof(float), stream);
        const long long total_units = (long long)n_edges * 32;
        const int fblocks = (int)((total_units + 255) / 256);
        gcn_fused_fallback<<<fblocks, 256, 0, stream>>>(x, W, esrc, edst, ew, out, total_units);
    }
}

// Round 18
// 93.942 us; speedup vs baseline: 1.3418x; 1.3418x over previous
//
#include <hip/hip_runtime.h>
#include <hip/hip_bf16.h>

#define IN_F 128
#define OUT_F 32
#define BSHIFT 7
#define NPB 128            // nodes per bucket (dst >> 7)
#define BCHUNK 4096        // edges per bin chunk
#define BIN_THREADS 1024
#define GAT_THREADS 512
#define TILE 2048          // recs per LDS tile in fused sort+gather
#define MAXBIN 1024
#define CAP 5120           // per-bucket region capacity (mean 4092 + 16 sigma)

static __device__ inline unsigned short f2bf_rne(float f) {
    unsigned u = __float_as_uint(f);
    unsigned r = u + 0x7FFF + ((u >> 16) & 1);   // round-to-nearest-even
    return (unsigned short)(r >> 16);
}

// ---------------- K1: h = x @ W, output bf16 (W staged in LDS) ----------------
__global__ void gcn_gemm_h(const float* __restrict__ x, const float* __restrict__ W,
                           unsigned short* __restrict__ h, int n_rows)
{
    __shared__ float Wl[IN_F * OUT_F];           // 16 KB
    const int tid = threadIdx.x;
    const float4* W4 = (const float4*)W;
    float4* Wl4 = (float4*)Wl;
    #pragma unroll
    for (int i = 0; i < 4; ++i)
        Wl4[tid + i * 256] = W4[tid + i * 256];
    __syncthreads();

    const int c4   = tid & 7;
    const int rloc = tid >> 3;
    const int row  = blockIdx.x * 32 + rloc;
    if (row >= n_rows) return;

    const float4* xr = (const float4*)(x + (size_t)row * IN_F);
    float4 acc = {0.f, 0.f, 0.f, 0.f};
    #pragma unroll
    for (int k4 = 0; k4 < IN_F / 4; ++k4) {
        const float4 xv = xr[k4];
        #pragma unroll
        for (int j = 0; j < 4; ++j) {
            const int k = k4 * 4 + j;
            const float4 wv = *(const float4*)(&Wl[k * OUT_F + c4 * 4]);
            const float xs = (&xv.x)[j];
            acc.x += xs * wv.x;
            acc.y += xs * wv.y;
            acc.z += xs * wv.z;
            acc.w += xs * wv.w;
        }
    }
    ushort4 o = { f2bf_rne(acc.x), f2bf_rne(acc.y), f2bf_rne(acc.z), f2bf_rne(acc.w) };
    *(ushort4*)(&h[(size_t)row * OUT_F + c4 * 4]) = o;
}

// ---------------- K2a: init per-bucket cursors ----------------
__global__ __launch_bounds__(1024)
void gcn_initcur(int* __restrict__ gcur, int nb)
{
    const int i = blockIdx.x * 1024 + threadIdx.x;
    if (i < nb) gcur[i] = i * CAP;
}

// ---------------- K2b: in-LDS counting sort by bucket + atomic-reserved copy-out ----
// 1024 threads (R13 config — latency-bound, maximize threads per chunk).
__global__ __launch_bounds__(BIN_THREADS)
void gcn_bin(const int* __restrict__ esrc, const int* __restrict__ edst,
             const float* __restrict__ ew, int* __restrict__ gcur,
             int2* __restrict__ recs, int n_edges, int nb)
{
    __shared__ int2 sorted[BCHUNK];              // 32 KB
    __shared__ unsigned short binOf[BCHUNK];     // 8 KB
    __shared__ int hist[MAXBIN];
    __shared__ int cursor[MAXBIN];
    __shared__ int gbase[MAXBIN];
    __shared__ int wpart[16];
    __shared__ int wpre[16];

    const int tid = threadIdx.x;
    const int k   = blockIdx.x;
    const int base  = k * BCHUNK;
    const int count = min(BCHUNK, n_edges - base);

    for (int i = tid; i < nb; i += BIN_THREADS) hist[i] = 0;
    __syncthreads();
    for (int i = tid; i < count; i += BIN_THREADS)
        atomicAdd(&hist[edst[base + i] >> BSHIFT], 1);
    __syncthreads();

    // exclusive scan of hist over nb (<=1024) entries: shfl scan + combine
    const int v = (tid < nb) ? hist[tid] : 0;
    int sc = v;
    #pragma unroll
    for (int off = 1; off < 64; off <<= 1) {
        const int t = __shfl_up(sc, off, 64);
        if ((tid & 63) >= off) sc += t;
    }
    if ((tid & 63) == 63) wpart[tid >> 6] = sc;
    __syncthreads();
    if (tid < 16) {
        const int pv = wpart[tid];
        int ps = pv;
        #pragma unroll
        for (int off = 1; off < 16; off <<= 1) {
            const int t = __shfl_up(ps, off, 64);
            if (tid >= off) ps += t;
        }
        wpre[tid] = ps - pv;
    }
    __syncthreads();
    if (tid < nb) {
        const int beg = sc - v + wpre[tid >> 6];   // local exclusive offset
        cursor[tid] = beg;
        int gb = 0;
        if (v > 0) gb = atomicAdd(&gcur[tid], v);  // reserve contiguous run
        gbase[tid] = gb - beg;
    }
    __syncthreads();

    // scatter into LDS sorted order (edges re-read, L2-hot)
    for (int i = tid; i < count; i += BIN_THREADS) {
        const int e = base + i;
        const int d = edst[e];
        const int bk = d >> BSHIFT;
        const int pos = atomicAdd(&cursor[bk], 1);
        sorted[pos] = make_int2(esrc[e] | ((d & (NPB - 1)) << 17), __float_as_int(ew[e]));
        binOf[pos]  = (unsigned short)bk;
    }
    __syncthreads();

    // linear copy-out: consecutive i within a run -> consecutive global addrs
    for (int i = tid; i < count; i += BIN_THREADS)
        recs[gbase[binOf[i]] + i] = sorted[i];
}

// ---------------- K3: fused per-bucket LDS sort + register gather ----------------
// 512 threads, ~34 KB LDS -> 4 blocks/CU. 128 groups of 4 lanes; each group owns
// ONE node; lane loads uint4 = 8 channels/rec (64 B/rec coalesced). Serial depth
// per tile = ~16 recs / 4-deep = 4 dependent load groups (4x less than R13).
__global__ __launch_bounds__(GAT_THREADS)
void gcn_sort_gather(const unsigned short* __restrict__ h,
                     const int2* __restrict__ recs,
                     const int* __restrict__ gcur,
                     float* __restrict__ out, int n_nodes)
{
    __shared__ int2 sbuf[TILE];       // 16 KB
    __shared__ int2 sorted[TILE];     // 16 KB
    __shared__ int hist[NPB];
    __shared__ int nbeg[NPB];
    __shared__ int cursor[NPB];
    __shared__ int wpart[2];

    const int b   = blockIdx.x;
    const int tid = threadIdx.x;
    const int s   = b * CAP;
    const int cnt = gcur[b] - s;       // records written for this bucket
    const int grp = tid >> 2;          // 0..127: group of 4 lanes, owns node grp
    const int q   = tid & 3;           // quarter of h-row: channels [8q, 8q+8)
    const size_t hoff = (size_t)(q << 3);

    float a0 = 0.f, a1 = 0.f, a2 = 0.f, a3 = 0.f;
    float a4 = 0.f, a5 = 0.f, a6 = 0.f, a7 = 0.f;

    for (int t0 = 0; t0 < cnt; t0 += TILE) {
        const int tc = min(TILE, cnt - t0);
        __syncthreads();               // previous tile's gather done before reuse
        if (tid < NPB) hist[tid] = 0;
        __syncthreads();
        for (int i = tid; i < tc; i += GAT_THREADS) {
            const int2 r = recs[s + t0 + i];
            sbuf[i] = r;
            atomicAdd(&hist[(r.x >> 17) & (NPB - 1)], 1);
        }
        __syncthreads();

        // exclusive scan over NPB=128 entries: shfl scan + 2-wave combine
        const int v = (tid < NPB) ? hist[tid] : 0;
        int sc = v;
        #pragma unroll
        for (int off = 1; off < 64; off <<= 1) {
            const int t = __shfl_up(sc, off, 64);
            if ((tid & 63) >= off) sc += t;
        }
        if (tid < NPB && (tid & 63) == 63) wpart[tid >> 6] = sc;
        __syncthreads();
        if (tid < NPB) {
            const int beg = sc - v + ((tid >= 64) ? wpart[0] : 0);
            nbeg[tid]   = beg;
            cursor[tid] = beg;
        }
        __syncthreads();

        for (int i = tid; i < tc; i += GAT_THREADS) {
            const int2 r = sbuf[i];
            const int pos = atomicAdd(&cursor[(r.x >> 17) & (NPB - 1)], 1);
            sorted[pos] = r;
        }
        __syncthreads();

        // gather: ONE node per 4-lane group; 4-deep pipelined inner loop
        {
            int i = nbeg[grp];
            const int e = i + hist[grp];
            for (; i + 4 <= e; i += 4) {
                const int2 r0 = sorted[i];
                const int2 r1 = sorted[i + 1];
                const int2 r2 = sorted[i + 2];
                const int2 r3 = sorted[i + 3];
                const uint4 v0 = *(const uint4*)(h + (((size_t)(r0.x & 0x1FFFF)) << 5) + hoff);
                const uint4 v1 = *(const uint4*)(h + (((size_t)(r1.x & 0x1FFFF)) << 5) + hoff);
                const uint4 v2 = *(const uint4*)(h + (((size_t)(r2.x & 0x1FFFF)) << 5) + hoff);
                const uint4 v3 = *(const uint4*)(h + (((size_t)(r3.x & 0x1FFFF)) << 5) + hoff);
                const float w0 = __int_as_float(r0.y);
                const float w1 = __int_as_float(r1.y);
                const float w2 = __int_as_float(r2.y);
                const float w3 = __int_as_float(r3.y);
                a0 += w0 * __uint_as_float(v0.x << 16);
                a1 += w0 * __uint_as_float(v0.x & 0xFFFF0000u);
                a2 += w0 * __uint_as_float(v0.y << 16);
                a3 += w0 * __uint_as_float(v0.y & 0xFFFF0000u);
                a4 += w0 * __uint_as_float(v0.z << 16);
                a5 += w0 * __uint_as_float(v0.z & 0xFFFF0000u);
                a6 += w0 * __uint_as_float(v0.w << 16);
                a7 += w0 * __uint_as_float(v0.w & 0xFFFF0000u);
                a0 += w1 * __uint_as_float(v1.x << 16);
                a1 += w1 * __uint_as_float(v1.x & 0xFFFF0000u);
                a2 += w1 * __uint_as_float(v1.y << 16);
                a3 += w1 * __uint_as_float(v1.y & 0xFFFF0000u);
                a4 += w1 * __uint_as_float(v1.z << 16);
                a5 += w1 * __uint_as_float(v1.z & 0xFFFF0000u);
                a6 += w1 * __uint_as_float(v1.w << 16);
                a7 += w1 * __uint_as_float(v1.w & 0xFFFF0000u);
                a0 += w2 * __uint_as_float(v2.x << 16);
                a1 += w2 * __uint_as_float(v2.x & 0xFFFF0000u);
                a2 += w2 * __uint_as_float(v2.y << 16);
                a3 += w2 * __uint_as_float(v2.y & 0xFFFF0000u);
                a4 += w2 * __uint_as_float(v2.z << 16);
                a5 += w2 * __uint_as_float(v2.z & 0xFFFF0000u);
                a6 += w2 * __uint_as_float(v2.w << 16);
                a7 += w2 * __uint_as_float(v2.w & 0xFFFF0000u);
                a0 += w3 * __uint_as_float(v3.x << 16);
                a1 += w3 * __uint_as_float(v3.x & 0xFFFF0000u);
                a2 += w3 * __uint_as_float(v3.y << 16);
                a3 += w3 * __uint_as_float(v3.y & 0xFFFF0000u);
                a4 += w3 * __uint_as_float(v3.z << 16);
                a5 += w3 * __uint_as_float(v3.z & 0xFFFF0000u);
                a6 += w3 * __uint_as_float(v3.w << 16);
                a7 += w3 * __uint_as_float(v3.w & 0xFFFF0000u);
            }
            for (; i < e; ++i) {
                const int2 r = sorted[i];
                const uint4 hv = *(const uint4*)(h + (((size_t)(r.x & 0x1FFFF)) << 5) + hoff);
                const float w = __int_as_float(r.y);
                a0 += w * __uint_as_float(hv.x << 16);
                a1 += w * __uint_as_float(hv.x & 0xFFFF0000u);
                a2 += w * __uint_as_float(hv.y << 16);
                a3 += w * __uint_as_float(hv.y & 0xFFFF0000u);
                a4 += w * __uint_as_float(hv.z << 16);
                a5 += w * __uint_as_float(hv.z & 0xFFFF0000u);
                a6 += w * __uint_as_float(hv.w << 16);
                a7 += w * __uint_as_float(hv.w & 0xFFFF0000u);
            }
        }
    }

    const int node = (b << BSHIFT) + grp;
    if (node < n_nodes) {
        float* op = out + ((size_t)node << 5) + (q << 3);
        float4 o0 = { a0, a1, a2, a3 };
        float4 o1 = { a4, a5, a6, a7 };
        *(float4*)(op)     = o0;
        *(float4*)(op + 4) = o1;
    }
}

// ---------------- Fallback (no/small ws): fused, atomics into out ----------------
__global__ void gcn_fused_fallback(const float* __restrict__ x, const float* __restrict__ W,
                                   const int* __restrict__ esrc,
                                   const int* __restrict__ edst,
                                   const float* __restrict__ ew,
                                   float* __restrict__ out,
                                   long long total_units)
{
    __shared__ float Wl[IN_F * OUT_F];
    const int tid = threadIdx.x;
    const float4* W4 = (const float4*)W;
    float4* Wl4 = (float4*)Wl;
    #pragma unroll
    for (int i = 0; i < 4; ++i)
        Wl4[tid + i * 256] = W4[tid + i * 256];
    __syncthreads();

    long long u = (long long)blockIdx.x * blockDim.x + threadIdx.x;
    if (u >= total_units) return;
    const int e = (int)(u >> 5);
    const int c = (int)(u & 31);
    const int s  = esrc[e];
    const int d  = edst[e];
    const float w = ew[e];

    const float4* xr = (const float4*)(x + (size_t)s * IN_F);
    float acc = 0.f;
    #pragma unroll
    for (int k4 = 0; k4 < IN_F / 4; ++k4) {
        const float4 xv = xr[k4];
        acc += xv.x * Wl[(k4 * 4 + 0) * OUT_F + c];
        acc += xv.y * Wl[(k4 * 4 + 1) * OUT_F + c];
        acc += xv.z * Wl[(k4 * 4 + 2) * OUT_F + c];
        acc += xv.w * Wl[(k4 * 4 + 3) * OUT_F + c];
    }
    atomicAdd(out + (size_t)d * OUT_F + c, w * acc);
}

static inline size_t align_up(size_t v, size_t a) { return (v + a - 1) & ~(a - 1); }

extern "C" void kernel_launch(void* const* d_in, const int* in_sizes, int n_in,
                              void* d_out, int out_size, void* d_ws, size_t ws_size,
                              hipStream_t stream)
{
    const float* x  = (const float*)d_in[0];
    const float* W  = (const float*)d_in[1];
    const int* esrc = (const int*)d_in[2];
    const int* edst = (const int*)d_in[3];
    const float* ew = (const float*)d_in[4];
    float* out = (float*)d_out;

    const int n_nodes = in_sizes[0] / IN_F;
    const int n_edges = in_sizes[2];

    const int nb       = (n_nodes + NPB - 1) >> BSHIFT;    // 782
    const int n_chunks = (n_edges + BCHUNK - 1) / BCHUNK;  // 782
    const int avg_per_bucket = n_edges / nb;

    const size_t h_bytes    = align_up((size_t)n_nodes * OUT_F * sizeof(unsigned short), 256);
    const size_t cur_bytes  = align_up((size_t)nb * sizeof(int), 256);
    const size_t recs_bytes = align_up((size_t)nb * CAP * sizeof(int2) + 16, 256);
    const size_t need = h_bytes + cur_bytes + recs_bytes;

    if (ws_size >= need && nb <= MAXBIN && avg_per_bucket + 16 * 64 < CAP) {
        char* p = (char*)d_ws;
        unsigned short* h = (unsigned short*)p;  p += h_bytes;
        int* gcur     = (int*)p;                 p += cur_bytes;
        int2* recs    = (int2*)p;

        const int gemm_blocks = (n_nodes + 31) / 32;
        gcn_gemm_h<<<gemm_blocks, 256, 0, stream>>>(x, W, h, n_nodes);

        gcn_initcur<<<(nb + 1023) / 1024, 1024, 0, stream>>>(gcur, nb);
        gcn_bin<<<n_chunks, BIN_THREADS, 0, stream>>>(esrc, edst, ew, gcur,
                                                      recs, n_edges, nb);
        gcn_sort_gather<<<nb, GAT_THREADS, 0, stream>>>(h, recs, gcur, out, n_nodes);
    } else {
        hipMemsetAsync(d_out, 0, (size_t)out_size * sizeof(float), stream);
        const long long total_units = (long long)n_edges * 32;
        const int fblocks = (int)((total_units + 255) / 256);
        gcn_fused_fallback<<<fblocks, 256, 0, stream>>>(x, W, esrc, edst, ew, out, total_units);
    }
}

// Round 19
// 93.664 us; speedup vs baseline: 1.3458x; 1.0030x over previous
//
#include <hip/hip_runtime.h>
#include <hip/hip_bf16.h>

#define IN_F 128
#define OUT_F 32
#define BSHIFT 7
#define NPB 128            // nodes per bucket (dst >> 7)
#define BCHUNK 4096        // edges per bin chunk (= 1024 threads x 4 edges)
#define BIN_THREADS 1024
#define GAT_THREADS 512
#define TILE 2048          // recs per LDS tile in fused sort+gather
#define MAXBIN 1024
#define CAP 5120           // per-bucket region capacity (mean 4092 + 16 sigma)

static __device__ inline unsigned short f2bf_rne(float f) {
    unsigned u = __float_as_uint(f);
    unsigned r = u + 0x7FFF + ((u >> 16) & 1);   // round-to-nearest-even
    return (unsigned short)(r >> 16);
}

// ---------------- K1: h = x @ W (W staged in LDS); block 0 also inits gcur ------
__global__ void gcn_gemm_h(const float* __restrict__ x, const float* __restrict__ W,
                           unsigned short* __restrict__ h, int n_rows,
                           int* __restrict__ gcur, int nb)
{
    __shared__ float Wl[IN_F * OUT_F];           // 16 KB
    const int tid = threadIdx.x;
    if (blockIdx.x == 0)
        for (int i = tid; i < nb; i += 256) gcur[i] = i * CAP;

    const float4* W4 = (const float4*)W;
    float4* Wl4 = (float4*)Wl;
    #pragma unroll
    for (int i = 0; i < 4; ++i)
        Wl4[tid + i * 256] = W4[tid + i * 256];
    __syncthreads();

    const int c4   = tid & 7;
    const int rloc = tid >> 3;
    const int row  = blockIdx.x * 32 + rloc;
    if (row >= n_rows) return;

    const float4* xr = (const float4*)(x + (size_t)row * IN_F);
    float4 acc = {0.f, 0.f, 0.f, 0.f};
    #pragma unroll
    for (int k4 = 0; k4 < IN_F / 4; ++k4) {
        const float4 xv = xr[k4];
        #pragma unroll
        for (int j = 0; j < 4; ++j) {
            const int k = k4 * 4 + j;
            const float4 wv = *(const float4*)(&Wl[k * OUT_F + c4 * 4]);
            const float xs = (&xv.x)[j];
            acc.x += xs * wv.x;
            acc.y += xs * wv.y;
            acc.z += xs * wv.z;
            acc.w += xs * wv.w;
        }
    }
    ushort4 o = { f2bf_rne(acc.x), f2bf_rne(acc.y), f2bf_rne(acc.z), f2bf_rne(acc.w) };
    *(ushort4*)(&h[(size_t)row * OUT_F + c4 * 4]) = o;
}

// ---------------- K2: in-LDS counting sort + atomic-reserved copy-out -----------
// Each thread owns 4 CONSECUTIVE edges, loaded once as int4/float4 and held in
// registers across all phases (no re-read; 4 independent chains per phase).
__global__ __launch_bounds__(BIN_THREADS)
void gcn_bin(const int* __restrict__ esrc, const int* __restrict__ edst,
             const float* __restrict__ ew, int* __restrict__ gcur,
             int2* __restrict__ recs, int n_edges, int nb)
{
    __shared__ int2 sorted[BCHUNK];              // 32 KB
    __shared__ unsigned short binOf[BCHUNK];     // 8 KB
    __shared__ int hist[MAXBIN];
    __shared__ int cursor[MAXBIN];
    __shared__ int gbase[MAXBIN];
    __shared__ int wpart[16];
    __shared__ int wpre[16];

    const int tid = threadIdx.x;
    const int k   = blockIdx.x;
    const int base  = k * BCHUNK;
    const int count = min(BCHUNK, n_edges - base);
    const int i0    = tid * 4;
    const bool full = (i0 + 3 < count);

    // one-shot vector preload, kept live across barriers
    int4 d4 = {0, 0, 0, 0};
    int4 s4 = {0, 0, 0, 0};
    float4 w4 = {0.f, 0.f, 0.f, 0.f};
    if (full) {
        d4 = ((const int4*)(edst + base))[tid];
        s4 = ((const int4*)(esrc + base))[tid];
        w4 = ((const float4*)(ew + base))[tid];
    } else {
        if (i0     < count) { d4.x = edst[base + i0];     s4.x = esrc[base + i0];     w4.x = ew[base + i0]; }
        if (i0 + 1 < count) { d4.y = edst[base + i0 + 1]; s4.y = esrc[base + i0 + 1]; w4.y = ew[base + i0 + 1]; }
        if (i0 + 2 < count) { d4.z = edst[base + i0 + 2]; s4.z = esrc[base + i0 + 2]; w4.z = ew[base + i0 + 2]; }
    }

    for (int i = tid; i < nb; i += BIN_THREADS) hist[i] = 0;
    __syncthreads();

    // histogram: 4 independent register-fed LDS atomics
    if (full) {
        atomicAdd(&hist[d4.x >> BSHIFT], 1);
        atomicAdd(&hist[d4.y >> BSHIFT], 1);
        atomicAdd(&hist[d4.z >> BSHIFT], 1);
        atomicAdd(&hist[d4.w >> BSHIFT], 1);
    } else {
        if (i0     < count) atomicAdd(&hist[d4.x >> BSHIFT], 1);
        if (i0 + 1 < count) atomicAdd(&hist[d4.y >> BSHIFT], 1);
        if (i0 + 2 < count) atomicAdd(&hist[d4.z >> BSHIFT], 1);
    }
    __syncthreads();

    // exclusive scan of hist over nb (<=1024) entries: shfl scan + combine
    const int v = (tid < nb) ? hist[tid] : 0;
    int sc = v;
    #pragma unroll
    for (int off = 1; off < 64; off <<= 1) {
        const int t = __shfl_up(sc, off, 64);
        if ((tid & 63) >= off) sc += t;
    }
    if ((tid & 63) == 63) wpart[tid >> 6] = sc;
    __syncthreads();
    if (tid < 16) {
        const int pv = wpart[tid];
        int ps = pv;
        #pragma unroll
        for (int off = 1; off < 16; off <<= 1) {
            const int t = __shfl_up(ps, off, 64);
            if (tid >= off) ps += t;
        }
        wpre[tid] = ps - pv;
    }
    __syncthreads();
    if (tid < nb) {
        const int beg = sc - v + wpre[tid >> 6];   // local exclusive offset
        cursor[tid] = beg;
        int gb = 0;
        if (v > 0) gb = atomicAdd(&gcur[tid], v);  // reserve contiguous run
        gbase[tid] = gb - beg;
    }
    __syncthreads();

    // scatter into LDS sorted order (from registers — no global re-read)
    if (full) {
        #pragma unroll
        for (int j = 0; j < 4; ++j) {
            const int d  = (&d4.x)[j];
            const int bk = d >> BSHIFT;
            const int pos = atomicAdd(&cursor[bk], 1);
            sorted[pos] = make_int2((&s4.x)[j] | ((d & (NPB - 1)) << 17),
                                    __float_as_int((&w4.x)[j]));
            binOf[pos]  = (unsigned short)bk;
        }
    } else {
        #pragma unroll
        for (int j = 0; j < 4; ++j) {
            if (i0 + j < count) {
                const int d  = (&d4.x)[j];
                const int bk = d >> BSHIFT;
                const int pos = atomicAdd(&cursor[bk], 1);
                sorted[pos] = make_int2((&s4.x)[j] | ((d & (NPB - 1)) << 17),
                                        __float_as_int((&w4.x)[j]));
                binOf[pos]  = (unsigned short)bk;
            }
        }
    }
    __syncthreads();

    // linear copy-out: 4 consecutive positions per thread (b128-mergeable reads)
    if (full) {
        #pragma unroll
        for (int j = 0; j < 4; ++j) {
            const int i = i0 + j;
            recs[gbase[binOf[i]] + i] = sorted[i];
        }
    } else {
        #pragma unroll
        for (int j = 0; j < 4; ++j) {
            const int i = i0 + j;
            if (i < count) recs[gbase[binOf[i]] + i] = sorted[i];
        }
    }
}

// ---------------- K3: fused per-bucket LDS sort + register gather (R18) ---------
// 512 threads, ~34 KB LDS -> 4 blocks/CU. 128 groups of 4 lanes; each group owns
// ONE node; lane loads uint4 = 8 channels/rec (64 B/rec coalesced).
__global__ __launch_bounds__(GAT_THREADS)
void gcn_sort_gather(const unsigned short* __restrict__ h,
                     const int2* __restrict__ recs,
                     const int* __restrict__ gcur,
                     float* __restrict__ out, int n_nodes)
{
    __shared__ int2 sbuf[TILE];       // 16 KB
    __shared__ int2 sorted[TILE];     // 16 KB
    __shared__ int hist[NPB];
    __shared__ int nbeg[NPB];
    __shared__ int cursor[NPB];
    __shared__ int wpart[2];

    const int b   = blockIdx.x;
    const int tid = threadIdx.x;
    const int s   = b * CAP;
    const int cnt = gcur[b] - s;       // records written for this bucket
    const int grp = tid >> 2;          // 0..127: group of 4 lanes, owns node grp
    const int q   = tid & 3;           // quarter of h-row: channels [8q, 8q+8)
    const size_t hoff = (size_t)(q << 3);

    float a0 = 0.f, a1 = 0.f, a2 = 0.f, a3 = 0.f;
    float a4 = 0.f, a5 = 0.f, a6 = 0.f, a7 = 0.f;

    for (int t0 = 0; t0 < cnt; t0 += TILE) {
        const int tc = min(TILE, cnt - t0);
        __syncthreads();               // previous tile's gather done before reuse
        if (tid < NPB) hist[tid] = 0;
        __syncthreads();
        for (int i = tid; i < tc; i += GAT_THREADS) {
            const int2 r = recs[s + t0 + i];
            sbuf[i] = r;
            atomicAdd(&hist[(r.x >> 17) & (NPB - 1)], 1);
        }
        __syncthreads();

        // exclusive scan over NPB=128 entries: shfl scan + 2-wave combine
        const int v = (tid < NPB) ? hist[tid] : 0;
        int sc = v;
        #pragma unroll
        for (int off = 1; off < 64; off <<= 1) {
            const int t = __shfl_up(sc, off, 64);
            if ((tid & 63) >= off) sc += t;
        }
        if (tid < NPB && (tid & 63) == 63) wpart[tid >> 6] = sc;
        __syncthreads();
        if (tid < NPB) {
            const int beg = sc - v + ((tid >= 64) ? wpart[0] : 0);
            nbeg[tid]   = beg;
            cursor[tid] = beg;
        }
        __syncthreads();

        for (int i = tid; i < tc; i += GAT_THREADS) {
            const int2 r = sbuf[i];
            const int pos = atomicAdd(&cursor[(r.x >> 17) & (NPB - 1)], 1);
            sorted[pos] = r;
        }
        __syncthreads();

        // gather: ONE node per 4-lane group; 4-deep pipelined inner loop
        {
            int i = nbeg[grp];
            const int e = i + hist[grp];
            for (; i + 4 <= e; i += 4) {
                const int2 r0 = sorted[i];
                const int2 r1 = sorted[i + 1];
                const int2 r2 = sorted[i + 2];
                const int2 r3 = sorted[i + 3];
                const uint4 v0 = *(const uint4*)(h + (((size_t)(r0.x & 0x1FFFF)) << 5) + hoff);
                const uint4 v1 = *(const uint4*)(h + (((size_t)(r1.x & 0x1FFFF)) << 5) + hoff);
                const uint4 v2 = *(const uint4*)(h + (((size_t)(r2.x & 0x1FFFF)) << 5) + hoff);
                const uint4 v3 = *(const uint4*)(h + (((size_t)(r3.x & 0x1FFFF)) << 5) + hoff);
                const float w0 = __int_as_float(r0.y);
                const float w1 = __int_as_float(r1.y);
                const float w2 = __int_as_float(r2.y);
                const float w3 = __int_as_float(r3.y);
                a0 += w0 * __uint_as_float(v0.x << 16);
                a1 += w0 * __uint_as_float(v0.x & 0xFFFF0000u);
                a2 += w0 * __uint_as_float(v0.y << 16);
                a3 += w0 * __uint_as_float(v0.y & 0xFFFF0000u);
                a4 += w0 * __uint_as_float(v0.z << 16);
                a5 += w0 * __uint_as_float(v0.z & 0xFFFF0000u);
                a6 += w0 * __uint_as_float(v0.w << 16);
                a7 += w0 * __uint_as_float(v0.w & 0xFFFF0000u);
                a0 += w1 * __uint_as_float(v1.x << 16);
                a1 += w1 * __uint_as_float(v1.x & 0xFFFF0000u);
                a2 += w1 * __uint_as_float(v1.y << 16);
                a3 += w1 * __uint_as_float(v1.y & 0xFFFF0000u);
                a4 += w1 * __uint_as_float(v1.z << 16);
                a5 += w1 * __uint_as_float(v1.z & 0xFFFF0000u);
                a6 += w1 * __uint_as_float(v1.w << 16);
                a7 += w1 * __uint_as_float(v1.w & 0xFFFF0000u);
                a0 += w2 * __uint_as_float(v2.x << 16);
                a1 += w2 * __uint_as_float(v2.x & 0xFFFF0000u);
                a2 += w2 * __uint_as_float(v2.y << 16);
                a3 += w2 * __uint_as_float(v2.y & 0xFFFF0000u);
                a4 += w2 * __uint_as_float(v2.z << 16);
                a5 += w2 * __uint_as_float(v2.z & 0xFFFF0000u);
                a6 += w2 * __uint_as_float(v2.w << 16);
                a7 += w2 * __uint_as_float(v2.w & 0xFFFF0000u);
                a0 += w3 * __uint_as_float(v3.x << 16);
                a1 += w3 * __uint_as_float(v3.x & 0xFFFF0000u);
                a2 += w3 * __uint_as_float(v3.y << 16);
                a3 += w3 * __uint_as_float(v3.y & 0xFFFF0000u);
                a4 += w3 * __uint_as_float(v3.z << 16);
                a5 += w3 * __uint_as_float(v3.z & 0xFFFF0000u);
                a6 += w3 * __uint_as_float(v3.w << 16);
                a7 += w3 * __uint_as_float(v3.w & 0xFFFF0000u);
            }
            for (; i < e; ++i) {
                const int2 r = sorted[i];
                const uint4 hv = *(const uint4*)(h + (((size_t)(r.x & 0x1FFFF)) << 5) + hoff);
                const float w = __int_as_float(r.y);
                a0 += w * __uint_as_float(hv.x << 16);
                a1 += w * __uint_as_float(hv.x & 0xFFFF0000u);
                a2 += w * __uint_as_float(hv.y << 16);
                a3 += w * __uint_as_float(hv.y & 0xFFFF0000u);
                a4 += w * __uint_as_float(hv.z << 16);
                a5 += w * __uint_as_float(hv.z & 0xFFFF0000u);
                a6 += w * __uint_as_float(hv.w << 16);
                a7 += w * __uint_as_float(hv.w & 0xFFFF0000u);
            }
        }
    }

    const int node = (b << BSHIFT) + grp;
    if (node < n_nodes) {
        float* op = out + ((size_t)node << 5) + (q << 3);
        float4 o0 = { a0, a1, a2, a3 };
        float4 o1 = { a4, a5, a6, a7 };
        *(float4*)(op)     = o0;
        *(float4*)(op + 4) = o1;
    }
}

// ---------------- Fallback (no/small ws): fused, atomics into out ----------------
__global__ void gcn_fused_fallback(const float* __restrict__ x, const float* __restrict__ W,
                                   const int* __restrict__ esrc,
                                   const int* __restrict__ edst,
                                   const float* __restrict__ ew,
                                   float* __restrict__ out,
                                   long long total_units)
{
    __shared__ float Wl[IN_F * OUT_F];
    const int tid = threadIdx.x;
    const float4* W4 = (const float4*)W;
    float4* Wl4 = (float4*)Wl;
    #pragma unroll
    for (int i = 0; i < 4; ++i)
        Wl4[tid + i * 256] = W4[tid + i * 256];
    __syncthreads();

    long long u = (long long)blockIdx.x * blockDim.x + threadIdx.x;
    if (u >= total_units) return;
    const int e = (int)(u >> 5);
    const int c = (int)(u & 31);
    const int s  = esrc[e];
    const int d  = edst[e];
    const float w = ew[e];

    const float4* xr = (const float4*)(x + (size_t)s * IN_F);
    float acc = 0.f;
    #pragma unroll
    for (int k4 = 0; k4 < IN_F / 4; ++k4) {
        const float4 xv = xr[k4];
        acc += xv.x * Wl[(k4 * 4 + 0) * OUT_F + c];
        acc += xv.y * Wl[(k4 * 4 + 1) * OUT_F + c];
        acc += xv.z * Wl[(k4 * 4 + 2) * OUT_F + c];
        acc += xv.w * Wl[(k4 * 4 + 3) * OUT_F + c];
    }
    atomicAdd(out + (size_t)d * OUT_F + c, w * acc);
}

static inline size_t align_up(size_t v, size_t a) { return (v + a - 1) & ~(a - 1); }

extern "C" void kernel_launch(void* const* d_in, const int* in_sizes, int n_in,
                              void* d_out, int out_size, void* d_ws, size_t ws_size,
                              hipStream_t stream)
{
    const float* x  = (const float*)d_in[0];
    const float* W  = (const float*)d_in[1];
    const int* esrc = (const int*)d_in[2];
    const int* edst = (const int*)d_in[3];
    const float* ew = (const float*)d_in[4];
    float* out = (float*)d_out;

    const int n_nodes = in_sizes[0] / IN_F;
    const int n_edges = in_sizes[2];

    const int nb       = (n_nodes + NPB - 1) >> BSHIFT;    // 782
    const int n_chunks = (n_edges + BCHUNK - 1) / BCHUNK;  // 782
    const int avg_per_bucket = n_edges / nb;

    const size_t h_bytes    = align_up((size_t)n_nodes * OUT_F * sizeof(unsigned short), 256);
    const size_t cur_bytes  = align_up((size_t)nb * sizeof(int), 256);
    const size_t recs_bytes = align_up((size_t)nb * CAP * sizeof(int2) + 16, 256);
    const size_t need = h_bytes + cur_bytes + recs_bytes;

    if (ws_size >= need && nb <= MAXBIN && avg_per_bucket + 16 * 64 < CAP) {
        char* p = (char*)d_ws;
        unsigned short* h = (unsigned short*)p;  p += h_bytes;
        int* gcur     = (int*)p;                 p += cur_bytes;
        int2* recs    = (int2*)p;

        const int gemm_blocks = (n_nodes + 31) / 32;
        gcn_gemm_h<<<gemm_blocks, 256, 0, stream>>>(x, W, h, n_nodes, gcur, nb);

        gcn_bin<<<n_chunks, BIN_THREADS, 0, stream>>>(esrc, edst, ew, gcur,
                                                      recs, n_edges, nb);
        gcn_sort_gather<<<nb, GAT_THREADS, 0, stream>>>(h, recs, gcur, out, n_nodes);
    } else {
        hipMemsetAsync(d_out, 0, (size_t)out_size * sizeof(float), stream);
        const long long total_units = (long long)n_edges * 32;
        const int fblocks = (int)((total_units + 255) / 256);
        gcn_fused_fallback<<<fblocks, 256, 0, stream>>>(x, W, esrc, edst, ew, out, total_units);
    }
}